// Round 2
// baseline (16159.157 us; speedup 1.0000x reference)
//
#include <hip/hip_runtime.h>

#define NB    1024
#define TSEQ  336
#define DIM   64
#define GATES 256
#define PRED  96
#define THREADS 1024

// LDS layout (float offsets) — IDENTICAL to the proven 512-thread kernel.
// Weights live in VGPRs: 64 floats/thread at 1024 thr (no AGPR spill).
// All matvec inputs are wave-uniform LDS b128 broadcasts (free) or wave-uniform
// global float4 loads (x); partial writes / combine reads are stride-1 b32.
#define P0O   0        // layer-0 partials [4 copies][4 rows][256 gates]
#define P1O   4096     // layer-1 partials [4][4][256]
#define WFCO  8192     // W_fc [16][4][64] : (k4,c,j) = W[j][4k4+c]
#define H0O   12288    // [4][64]
#define H1O   12544    // [4][64]
#define DBO   12800    // [4][64] decoder feedback
#define BS0O  13056    // 256
#define BS1O  13312    // 256
#define BFCO  13568    // 64
#define SMF   13632
#define SMEM_BYTES (SMF * 4)

__device__ __forceinline__ float sigm(float v)  { return 1.0f / (1.0f + __expf(-v)); }
__device__ __forceinline__ float tanh_(float v) { return 1.0f - 2.0f / (__expf(2.0f * v) + 1.0f); }

__device__ __forceinline__ void fma4v(float& acc, const float4 xv, const float4 w) {
    acc = fmaf(xv.x, w.x, acc); acc = fmaf(xv.y, w.y, acc);
    acc = fmaf(xv.z, w.z, acc); acc = fmaf(xv.w, w.w, acc);
}

extern "C" __global__ void __launch_bounds__(THREADS, 4)
rnn_fused(const float* __restrict__ x,
          const float* __restrict__ Wih0, const float* __restrict__ Whh0,
          const float* __restrict__ bih0, const float* __restrict__ bhh0,
          const float* __restrict__ Wih1, const float* __restrict__ Whh1,
          const float* __restrict__ bih1, const float* __restrict__ bhh1,
          const float* __restrict__ Wfc,  const float* __restrict__ bfc,
          float* __restrict__ out)
{
    extern __shared__ float sm[];
    const int tid = threadIdx.x;
    const int bid = blockIdx.x;
    const int grp = tid >> 8;          // 0..3 (wave-uniform): copy index
    const int m   = grp & 1;           // 0: ih matrix, 1: hh matrix
    const int kh  = grp >> 1;          // k-half: k in [kh*32, kh*32+32)
    const int g0  = tid & 255;         // owned gate row (ONE gate per lane)
    const int rr  = (tid & 255) >> 6;  // combine row
    const int jj  = tid & 63;          // combine hidden index

    // ---- prologue staging (biases, W_fc, zero states) ----
    if (tid < GATES) {
        sm[BS0O + tid] = bih0[tid] + bhh0[tid];
        sm[BS1O + tid] = bih1[tid] + bhh1[tid];
    }
    if (tid < DIM) sm[BFCO + tid] = bfc[tid];
    if (tid < 256) { sm[H0O + tid] = 0.0f; sm[H1O + tid] = 0.0f; }
    for (int idx = tid; idx < DIM * DIM; idx += THREADS) {   // W_fc: (k4,c,j)
        const int j = idx >> 6, k = idx & 63;
        sm[WFCO + (k >> 2) * 256 + (k & 3) * 64 + j] = Wfc[idx];
    }

    // ---- recurrent weights in registers: 16 float4 = 64 VGPR/thread ----
    const float* Wsrc0 = m ? Whh0 : Wih0;
    const float* Wsrc1 = m ? Whh1 : Wih1;
    float4 w0[8], w1[8];
#pragma unroll
    for (int k4 = 0; k4 < 8; ++k4) {
        w0[k4] = *reinterpret_cast<const float4*>(Wsrc0 + g0 * DIM + kh * 32 + k4 * 4);
        w1[k4] = *reinterpret_cast<const float4*>(Wsrc1 + g0 * DIM + kh * 32 + k4 * 4);
    }
    __syncthreads();

    const int row0 = bid * 4;
    const float* xr0 = x + (size_t)(row0 + 0) * TSEQ * DIM + kh * 32;
    const float* xr1 = x + (size_t)(row0 + 1) * TSEQ * DIM + kh * 32;
    const float* xr2 = x + (size_t)(row0 + 2) * TSEQ * DIM + kh * 32;
    const float* xr3 = x + (size_t)(row0 + 3) * TSEQ * DIM + kh * 32;

    const int pb = grp * 1024;         // this group's partial-copy base
    float c_state = 0.0f;              // c0 for tid<256; c1 for tid in [256,512)

    // ============ encoder: 336 steps, 3 barriers (combine1_{s-1} overlaps seg1) ============
    for (int s = 0; s < TSEQ; ++s) {
        // ---- seg1: combine1(s-1) on lanes [256,512), + layer-0 matvec on all ----
        if (s != 0 && tid >= 256 && tid < 512) {
            float pi = sm[BS1O + jj],       pf = sm[BS1O + 64 + jj];
            float pg = sm[BS1O + 128 + jj], po = sm[BS1O + 192 + jj];
#pragma unroll
            for (int cp = 0; cp < 4; ++cp) {
                const float* p = sm + P1O + cp * 1024 + rr * 256;
                pi += p[jj]; pf += p[64 + jj]; pg += p[128 + jj]; po += p[192 + jj];
            }
            const float ig = sigm(pi), fg = sigm(pf), gg = tanh_(pg), og = sigm(po);
            c_state = fmaf(fg, c_state, ig * gg);
            sm[H1O + (tid & 255)] = og * tanh_(c_state);
        }
        {
            float acc[4] = {0.f, 0.f, 0.f, 0.f};
            if (m == 0) {        // x-part: wave-uniform GLOBAL loads (VMEM pipe)
                const int so = s * DIM;
#pragma unroll
                for (int k4 = 0; k4 < 8; ++k4) {
                    const float4 v0 = *reinterpret_cast<const float4*>(xr0 + so + k4 * 4);
                    const float4 v1 = *reinterpret_cast<const float4*>(xr1 + so + k4 * 4);
                    const float4 v2 = *reinterpret_cast<const float4*>(xr2 + so + k4 * 4);
                    const float4 v3 = *reinterpret_cast<const float4*>(xr3 + so + k4 * 4);
                    fma4v(acc[0], v0, w0[k4]);
                    fma4v(acc[1], v1, w0[k4]);
                    fma4v(acc[2], v2, w0[k4]);
                    fma4v(acc[3], v3, w0[k4]);
                }
            } else {             // h-part: wave-uniform LDS b128 broadcasts (free)
#pragma unroll
                for (int k4 = 0; k4 < 8; ++k4) {
                    const float4 v0 = *reinterpret_cast<const float4*>(sm + H0O + 0 * 64 + kh * 32 + k4 * 4);
                    const float4 v1 = *reinterpret_cast<const float4*>(sm + H0O + 1 * 64 + kh * 32 + k4 * 4);
                    const float4 v2 = *reinterpret_cast<const float4*>(sm + H0O + 2 * 64 + kh * 32 + k4 * 4);
                    const float4 v3 = *reinterpret_cast<const float4*>(sm + H0O + 3 * 64 + kh * 32 + k4 * 4);
                    fma4v(acc[0], v0, w0[k4]);
                    fma4v(acc[1], v1, w0[k4]);
                    fma4v(acc[2], v2, w0[k4]);
                    fma4v(acc[3], v3, w0[k4]);
                }
            }
            sm[P0O + pb + 0 * 256 + g0] = acc[0];
            sm[P0O + pb + 1 * 256 + g0] = acc[1];
            sm[P0O + pb + 2 * 256 + g0] = acc[2];
            sm[P0O + pb + 3 * 256 + g0] = acc[3];
        }
        __syncthreads();

        // ---- seg2: combine0 (tid<256) ----
        if (tid < 256) {
            float pi = sm[BS0O + jj],       pf = sm[BS0O + 64 + jj];
            float pg = sm[BS0O + 128 + jj], po = sm[BS0O + 192 + jj];
#pragma unroll
            for (int cp = 0; cp < 4; ++cp) {
                const float* p = sm + P0O + cp * 1024 + rr * 256;
                pi += p[jj]; pf += p[64 + jj]; pg += p[128 + jj]; po += p[192 + jj];
            }
            const float ig = sigm(pi), fg = sigm(pf), gg = tanh_(pg), og = sigm(po);
            c_state = fmaf(fg, c_state, ig * gg);
            sm[H0O + tid] = og * tanh_(c_state);
        }
        __syncthreads();

        // ---- seg3: layer-1 matvec (register weights; m selects h0_s / h1_{s-1}) ----
        {
            const int ib = m ? H1O : H0O;
            float acc[4] = {0.f, 0.f, 0.f, 0.f};
#pragma unroll
            for (int k4 = 0; k4 < 8; ++k4) {
                const float4 v0 = *reinterpret_cast<const float4*>(sm + ib + 0 * 64 + kh * 32 + k4 * 4);
                const float4 v1 = *reinterpret_cast<const float4*>(sm + ib + 1 * 64 + kh * 32 + k4 * 4);
                const float4 v2 = *reinterpret_cast<const float4*>(sm + ib + 2 * 64 + kh * 32 + k4 * 4);
                const float4 v3 = *reinterpret_cast<const float4*>(sm + ib + 3 * 64 + kh * 32 + k4 * 4);
                fma4v(acc[0], v0, w1[k4]);
                fma4v(acc[1], v1, w1[k4]);
                fma4v(acc[2], v2, w1[k4]);
                fma4v(acc[3], v3, w1[k4]);
            }
            sm[P1O + pb + 0 * 256 + g0] = acc[0];
            sm[P1O + pb + 1 * 256 + g0] = acc[1];
            sm[P1O + pb + 2 * 256 + g0] = acc[2];
            sm[P1O + pb + 3 * 256 + g0] = acc[3];
        }
        __syncthreads();
    }

    // ---- final combine1 (s=335) -> decoder carry ----
    if (tid >= 256 && tid < 512) {
        float pi = sm[BS1O + jj],       pf = sm[BS1O + 64 + jj];
        float pg = sm[BS1O + 128 + jj], po = sm[BS1O + 192 + jj];
#pragma unroll
        for (int cp = 0; cp < 4; ++cp) {
            const float* p = sm + P1O + cp * 1024 + rr * 256;
            pi += p[jj]; pf += p[64 + jj]; pg += p[128 + jj]; po += p[192 + jj];
        }
        const float ig = sigm(pi), fg = sigm(pf), gg = tanh_(pg), og = sigm(po);
        c_state = fmaf(fg, c_state, ig * gg);
        sm[DBO + (tid & 255)] = og * tanh_(c_state);
    }
    __syncthreads();

    const float bfc_j = sm[BFCO + jj];

    // ============ decoder: 96 autoregressive steps (zero-state cells) ============
    for (int p = 0; p < PRED; ++p) {
        // ---- seg1: cell0 = db@Wih0^T (m==0 groups; copies 0 and 2) ----
        if (m == 0) {
            float acc[4] = {0.f, 0.f, 0.f, 0.f};
#pragma unroll
            for (int k4 = 0; k4 < 8; ++k4) {
                const float4 v0 = *reinterpret_cast<const float4*>(sm + DBO + 0 * 64 + kh * 32 + k4 * 4);
                const float4 v1 = *reinterpret_cast<const float4*>(sm + DBO + 1 * 64 + kh * 32 + k4 * 4);
                const float4 v2 = *reinterpret_cast<const float4*>(sm + DBO + 2 * 64 + kh * 32 + k4 * 4);
                const float4 v3 = *reinterpret_cast<const float4*>(sm + DBO + 3 * 64 + kh * 32 + k4 * 4);
                fma4v(acc[0], v0, w0[k4]);
                fma4v(acc[1], v1, w0[k4]);
                fma4v(acc[2], v2, w0[k4]);
                fma4v(acc[3], v3, w0[k4]);
            }
            sm[P0O + pb + 0 * 256 + g0] = acc[0];
            sm[P0O + pb + 1 * 256 + g0] = acc[1];
            sm[P0O + pb + 2 * 256 + g0] = acc[2];
            sm[P0O + pb + 3 * 256 + g0] = acc[3];
        }
        __syncthreads();
        if (tid < 256) {   // combine0 zero-state: c=i*g
            float pi = sm[BS0O + jj], pg = sm[BS0O + 128 + jj], po = sm[BS0O + 192 + jj];
            {
                const float* pA = sm + P0O + 0 * 1024 + rr * 256;
                const float* pB = sm + P0O + 2 * 1024 + rr * 256;
                pi += pA[jj] + pB[jj];
                pg += pA[128 + jj] + pB[128 + jj];
                po += pA[192 + jj] + pB[192 + jj];
            }
            const float ig = sigm(pi), gg = tanh_(pg), og = sigm(po);
            sm[H0O + tid] = og * tanh_(ig * gg);
        }
        __syncthreads();

        // ---- seg3: cell1 = h0@Wih1^T (m==0 groups) ----
        if (m == 0) {
            float acc[4] = {0.f, 0.f, 0.f, 0.f};
#pragma unroll
            for (int k4 = 0; k4 < 8; ++k4) {
                const float4 v0 = *reinterpret_cast<const float4*>(sm + H0O + 0 * 64 + kh * 32 + k4 * 4);
                const float4 v1 = *reinterpret_cast<const float4*>(sm + H0O + 1 * 64 + kh * 32 + k4 * 4);
                const float4 v2 = *reinterpret_cast<const float4*>(sm + H0O + 2 * 64 + kh * 32 + k4 * 4);
                const float4 v3 = *reinterpret_cast<const float4*>(sm + H0O + 3 * 64 + kh * 32 + k4 * 4);
                fma4v(acc[0], v0, w1[k4]);
                fma4v(acc[1], v1, w1[k4]);
                fma4v(acc[2], v2, w1[k4]);
                fma4v(acc[3], v3, w1[k4]);
            }
            sm[P1O + pb + 0 * 256 + g0] = acc[0];
            sm[P1O + pb + 1 * 256 + g0] = acc[1];
            sm[P1O + pb + 2 * 256 + g0] = acc[2];
            sm[P1O + pb + 3 * 256 + g0] = acc[3];
        }
        __syncthreads();
        if (tid >= 256 && tid < 512) {  // combine1 zero-state
            float pi = sm[BS1O + jj], pg = sm[BS1O + 128 + jj], po = sm[BS1O + 192 + jj];
            {
                const float* pA = sm + P1O + 0 * 1024 + rr * 256;
                const float* pB = sm + P1O + 2 * 1024 + rr * 256;
                pi += pA[jj] + pB[jj];
                pg += pA[128 + jj] + pB[128 + jj];
                po += pA[192 + jj] + pB[192 + jj];
            }
            const float ig = sigm(pi), gg = tanh_(pg), og = sigm(po);
            sm[H1O + (tid & 255)] = og * tanh_(ig * gg);
        }
        __syncthreads();

        // ---- seg5: FC (tid<256): stride-1 b32 W_fc reads + uniform h1 b128 ----
        if (tid < 256) {
            float acc = bfc_j;
            const float4* hp = reinterpret_cast<const float4*>(sm + H1O + rr * 64);
#pragma unroll
            for (int k4 = 0; k4 < 16; ++k4) {
                const float4 hv = hp[k4];
                const float* wp = sm + WFCO + k4 * 256;
                acc = fmaf(hv.x, wp[jj],       acc);
                acc = fmaf(hv.y, wp[64 + jj],  acc);
                acc = fmaf(hv.z, wp[128 + jj], acc);
                acc = fmaf(hv.w, wp[192 + jj], acc);
            }
            out[(size_t)(row0 + rr) * PRED * DIM + p * DIM + jj] = acc;
            sm[DBO + tid] = acc;
        }
        __syncthreads();
    }
}

extern "C" void kernel_launch(void* const* d_in, const int* in_sizes, int n_in,
                              void* d_out, int out_size, void* d_ws, size_t ws_size,
                              hipStream_t stream) {
    const float* x    = (const float*)d_in[0];
    const float* Wih0 = (const float*)d_in[1];
    const float* Whh0 = (const float*)d_in[2];
    const float* bih0 = (const float*)d_in[3];
    const float* bhh0 = (const float*)d_in[4];
    const float* Wih1 = (const float*)d_in[5];
    const float* Whh1 = (const float*)d_in[6];
    const float* bih1 = (const float*)d_in[7];
    const float* bhh1 = (const float*)d_in[8];
    const float* Wfc  = (const float*)d_in[9];
    const float* bfc  = (const float*)d_in[10];
    float* out = (float*)d_out;

    hipLaunchKernelGGL(rnn_fused, dim3(NB / 4), dim3(THREADS), SMEM_BYTES, stream,
                       x, Wih0, Whh0, bih0, bhh0, Wih1, Whh1, bih1, bhh1, Wfc, bfc, out);
}

// Round 3
// 15693.037 us; speedup vs baseline: 1.0297x; 1.0297x over previous
//
#include <hip/hip_runtime.h>

#define NB    1024
#define TSEQ  336
#define DIM   64
#define GATES 256
#define PRED  96
#define THREADS 1024

// LDS layout (float offsets) — IDENTICAL to the proven 512-thread kernel.
// Weights live in VGPRs: 64 floats/thread at 1024 thr.
// NOTE: __launch_bounds__ second arg MUST be 1 here. (1024, 4) made the
// compiler target 8 waves/SIMD -> 64-VGPR cap -> full weight spill to
// scratch -> 40 GB of HBM traffic and 9x slowdown (R2 post-mortem).
#define P0O   0        // layer-0 partials [4 copies][4 rows][256 gates]
#define P1O   4096     // layer-1 partials [4][4][256]
#define WFCO  8192     // W_fc [16][4][64] : (k4,c,j) = W[j][4k4+c]
#define H0O   12288    // [4][64]
#define H1O   12544    // [4][64]
#define DBO   12800    // [4][64] decoder feedback
#define BS0O  13056    // 256
#define BS1O  13312    // 256
#define BFCO  13568    // 64
#define SMF   13632
#define SMEM_BYTES (SMF * 4)

__device__ __forceinline__ float sigm(float v)  { return 1.0f / (1.0f + __expf(-v)); }
__device__ __forceinline__ float tanh_(float v) { return 1.0f - 2.0f / (__expf(2.0f * v) + 1.0f); }

__device__ __forceinline__ void fma4v(float& acc, const float4 xv, const float4 w) {
    acc = fmaf(xv.x, w.x, acc); acc = fmaf(xv.y, w.y, acc);
    acc = fmaf(xv.z, w.z, acc); acc = fmaf(xv.w, w.w, acc);
}

extern "C" __global__ void __launch_bounds__(THREADS, 1)
rnn_fused(const float* __restrict__ x,
          const float* __restrict__ Wih0, const float* __restrict__ Whh0,
          const float* __restrict__ bih0, const float* __restrict__ bhh0,
          const float* __restrict__ Wih1, const float* __restrict__ Whh1,
          const float* __restrict__ bih1, const float* __restrict__ bhh1,
          const float* __restrict__ Wfc,  const float* __restrict__ bfc,
          float* __restrict__ out)
{
    extern __shared__ float sm[];
    const int tid = threadIdx.x;
    const int bid = blockIdx.x;
    const int grp = tid >> 8;          // 0..3 (wave-uniform): copy index
    const int m   = grp & 1;           // 0: ih matrix, 1: hh matrix
    const int kh  = grp >> 1;          // k-half: k in [kh*32, kh*32+32)
    const int g0  = tid & 255;         // owned gate row (ONE gate per lane)
    const int rr  = (tid & 255) >> 6;  // combine row
    const int jj  = tid & 63;          // combine hidden index

    // ---- prologue staging (biases, W_fc, zero states) ----
    if (tid < GATES) {
        sm[BS0O + tid] = bih0[tid] + bhh0[tid];
        sm[BS1O + tid] = bih1[tid] + bhh1[tid];
    }
    if (tid < DIM) sm[BFCO + tid] = bfc[tid];
    if (tid < 256) { sm[H0O + tid] = 0.0f; sm[H1O + tid] = 0.0f; }
    for (int idx = tid; idx < DIM * DIM; idx += THREADS) {   // W_fc: (k4,c,j)
        const int j = idx >> 6, k = idx & 63;
        sm[WFCO + (k >> 2) * 256 + (k & 3) * 64 + j] = Wfc[idx];
    }

    // ---- recurrent weights in registers: 16 float4 = 64 VGPR/thread ----
    const float* Wsrc0 = m ? Whh0 : Wih0;
    const float* Wsrc1 = m ? Whh1 : Wih1;
    float4 w0[8], w1[8];
#pragma unroll
    for (int k4 = 0; k4 < 8; ++k4) {
        w0[k4] = *reinterpret_cast<const float4*>(Wsrc0 + g0 * DIM + kh * 32 + k4 * 4);
        w1[k4] = *reinterpret_cast<const float4*>(Wsrc1 + g0 * DIM + kh * 32 + k4 * 4);
    }
    __syncthreads();

    const int row0 = bid * 4;
    const float* xr0 = x + (size_t)(row0 + 0) * TSEQ * DIM + kh * 32;
    const float* xr1 = x + (size_t)(row0 + 1) * TSEQ * DIM + kh * 32;
    const float* xr2 = x + (size_t)(row0 + 2) * TSEQ * DIM + kh * 32;
    const float* xr3 = x + (size_t)(row0 + 3) * TSEQ * DIM + kh * 32;

    const int pb = grp * 1024;         // this group's partial-copy base
    float c_state = 0.0f;              // c0 for tid<256; c1 for tid in [256,512)

    // ============ encoder: 336 steps, 3 barriers (combine1_{s-1} overlaps seg1) ============
    for (int s = 0; s < TSEQ; ++s) {
        // ---- seg1: combine1(s-1) on lanes [256,512), + layer-0 matvec on all ----
        if (s != 0 && tid >= 256 && tid < 512) {
            float pi = sm[BS1O + jj],       pf = sm[BS1O + 64 + jj];
            float pg = sm[BS1O + 128 + jj], po = sm[BS1O + 192 + jj];
#pragma unroll
            for (int cp = 0; cp < 4; ++cp) {
                const float* p = sm + P1O + cp * 1024 + rr * 256;
                pi += p[jj]; pf += p[64 + jj]; pg += p[128 + jj]; po += p[192 + jj];
            }
            const float ig = sigm(pi), fg = sigm(pf), gg = tanh_(pg), og = sigm(po);
            c_state = fmaf(fg, c_state, ig * gg);
            sm[H1O + (tid & 255)] = og * tanh_(c_state);
        }
        {
            float acc[4] = {0.f, 0.f, 0.f, 0.f};
            if (m == 0) {        // x-part: wave-uniform GLOBAL loads (VMEM pipe)
                const int so = s * DIM;
#pragma unroll
                for (int k4 = 0; k4 < 8; ++k4) {
                    const float4 v0 = *reinterpret_cast<const float4*>(xr0 + so + k4 * 4);
                    const float4 v1 = *reinterpret_cast<const float4*>(xr1 + so + k4 * 4);
                    const float4 v2 = *reinterpret_cast<const float4*>(xr2 + so + k4 * 4);
                    const float4 v3 = *reinterpret_cast<const float4*>(xr3 + so + k4 * 4);
                    fma4v(acc[0], v0, w0[k4]);
                    fma4v(acc[1], v1, w0[k4]);
                    fma4v(acc[2], v2, w0[k4]);
                    fma4v(acc[3], v3, w0[k4]);
                }
            } else {             // h-part: wave-uniform LDS b128 broadcasts (free)
#pragma unroll
                for (int k4 = 0; k4 < 8; ++k4) {
                    const float4 v0 = *reinterpret_cast<const float4*>(sm + H0O + 0 * 64 + kh * 32 + k4 * 4);
                    const float4 v1 = *reinterpret_cast<const float4*>(sm + H0O + 1 * 64 + kh * 32 + k4 * 4);
                    const float4 v2 = *reinterpret_cast<const float4*>(sm + H0O + 2 * 64 + kh * 32 + k4 * 4);
                    const float4 v3 = *reinterpret_cast<const float4*>(sm + H0O + 3 * 64 + kh * 32 + k4 * 4);
                    fma4v(acc[0], v0, w0[k4]);
                    fma4v(acc[1], v1, w0[k4]);
                    fma4v(acc[2], v2, w0[k4]);
                    fma4v(acc[3], v3, w0[k4]);
                }
            }
            sm[P0O + pb + 0 * 256 + g0] = acc[0];
            sm[P0O + pb + 1 * 256 + g0] = acc[1];
            sm[P0O + pb + 2 * 256 + g0] = acc[2];
            sm[P0O + pb + 3 * 256 + g0] = acc[3];
        }
        __syncthreads();

        // ---- seg2: combine0 (tid<256) ----
        if (tid < 256) {
            float pi = sm[BS0O + jj],       pf = sm[BS0O + 64 + jj];
            float pg = sm[BS0O + 128 + jj], po = sm[BS0O + 192 + jj];
#pragma unroll
            for (int cp = 0; cp < 4; ++cp) {
                const float* p = sm + P0O + cp * 1024 + rr * 256;
                pi += p[jj]; pf += p[64 + jj]; pg += p[128 + jj]; po += p[192 + jj];
            }
            const float ig = sigm(pi), fg = sigm(pf), gg = tanh_(pg), og = sigm(po);
            c_state = fmaf(fg, c_state, ig * gg);
            sm[H0O + tid] = og * tanh_(c_state);
        }
        __syncthreads();

        // ---- seg3: layer-1 matvec (register weights; m selects h0_s / h1_{s-1}) ----
        {
            const int ib = m ? H1O : H0O;
            float acc[4] = {0.f, 0.f, 0.f, 0.f};
#pragma unroll
            for (int k4 = 0; k4 < 8; ++k4) {
                const float4 v0 = *reinterpret_cast<const float4*>(sm + ib + 0 * 64 + kh * 32 + k4 * 4);
                const float4 v1 = *reinterpret_cast<const float4*>(sm + ib + 1 * 64 + kh * 32 + k4 * 4);
                const float4 v2 = *reinterpret_cast<const float4*>(sm + ib + 2 * 64 + kh * 32 + k4 * 4);
                const float4 v3 = *reinterpret_cast<const float4*>(sm + ib + 3 * 64 + kh * 32 + k4 * 4);
                fma4v(acc[0], v0, w1[k4]);
                fma4v(acc[1], v1, w1[k4]);
                fma4v(acc[2], v2, w1[k4]);
                fma4v(acc[3], v3, w1[k4]);
            }
            sm[P1O + pb + 0 * 256 + g0] = acc[0];
            sm[P1O + pb + 1 * 256 + g0] = acc[1];
            sm[P1O + pb + 2 * 256 + g0] = acc[2];
            sm[P1O + pb + 3 * 256 + g0] = acc[3];
        }
        __syncthreads();
    }

    // ---- final combine1 (s=335) -> decoder carry ----
    if (tid >= 256 && tid < 512) {
        float pi = sm[BS1O + jj],       pf = sm[BS1O + 64 + jj];
        float pg = sm[BS1O + 128 + jj], po = sm[BS1O + 192 + jj];
#pragma unroll
        for (int cp = 0; cp < 4; ++cp) {
            const float* p = sm + P1O + cp * 1024 + rr * 256;
            pi += p[jj]; pf += p[64 + jj]; pg += p[128 + jj]; po += p[192 + jj];
        }
        const float ig = sigm(pi), fg = sigm(pf), gg = tanh_(pg), og = sigm(po);
        c_state = fmaf(fg, c_state, ig * gg);
        sm[DBO + (tid & 255)] = og * tanh_(c_state);
    }
    __syncthreads();

    const float bfc_j = sm[BFCO + jj];

    // ============ decoder: 96 autoregressive steps (zero-state cells) ============
    for (int p = 0; p < PRED; ++p) {
        // ---- seg1: cell0 = db@Wih0^T (m==0 groups; copies 0 and 2) ----
        if (m == 0) {
            float acc[4] = {0.f, 0.f, 0.f, 0.f};
#pragma unroll
            for (int k4 = 0; k4 < 8; ++k4) {
                const float4 v0 = *reinterpret_cast<const float4*>(sm + DBO + 0 * 64 + kh * 32 + k4 * 4);
                const float4 v1 = *reinterpret_cast<const float4*>(sm + DBO + 1 * 64 + kh * 32 + k4 * 4);
                const float4 v2 = *reinterpret_cast<const float4*>(sm + DBO + 2 * 64 + kh * 32 + k4 * 4);
                const float4 v3 = *reinterpret_cast<const float4*>(sm + DBO + 3 * 64 + kh * 32 + k4 * 4);
                fma4v(acc[0], v0, w0[k4]);
                fma4v(acc[1], v1, w0[k4]);
                fma4v(acc[2], v2, w0[k4]);
                fma4v(acc[3], v3, w0[k4]);
            }
            sm[P0O + pb + 0 * 256 + g0] = acc[0];
            sm[P0O + pb + 1 * 256 + g0] = acc[1];
            sm[P0O + pb + 2 * 256 + g0] = acc[2];
            sm[P0O + pb + 3 * 256 + g0] = acc[3];
        }
        __syncthreads();
        if (tid < 256) {   // combine0 zero-state: c=i*g
            float pi = sm[BS0O + jj], pg = sm[BS0O + 128 + jj], po = sm[BS0O + 192 + jj];
            {
                const float* pA = sm + P0O + 0 * 1024 + rr * 256;
                const float* pB = sm + P0O + 2 * 1024 + rr * 256;
                pi += pA[jj] + pB[jj];
                pg += pA[128 + jj] + pB[128 + jj];
                po += pA[192 + jj] + pB[192 + jj];
            }
            const float ig = sigm(pi), gg = tanh_(pg), og = sigm(po);
            sm[H0O + tid] = og * tanh_(ig * gg);
        }
        __syncthreads();

        // ---- seg3: cell1 = h0@Wih1^T (m==0 groups) ----
        if (m == 0) {
            float acc[4] = {0.f, 0.f, 0.f, 0.f};
#pragma unroll
            for (int k4 = 0; k4 < 8; ++k4) {
                const float4 v0 = *reinterpret_cast<const float4*>(sm + H0O + 0 * 64 + kh * 32 + k4 * 4);
                const float4 v1 = *reinterpret_cast<const float4*>(sm + H0O + 1 * 64 + kh * 32 + k4 * 4);
                const float4 v2 = *reinterpret_cast<const float4*>(sm + H0O + 2 * 64 + kh * 32 + k4 * 4);
                const float4 v3 = *reinterpret_cast<const float4*>(sm + H0O + 3 * 64 + kh * 32 + k4 * 4);
                fma4v(acc[0], v0, w1[k4]);
                fma4v(acc[1], v1, w1[k4]);
                fma4v(acc[2], v2, w1[k4]);
                fma4v(acc[3], v3, w1[k4]);
            }
            sm[P1O + pb + 0 * 256 + g0] = acc[0];
            sm[P1O + pb + 1 * 256 + g0] = acc[1];
            sm[P1O + pb + 2 * 256 + g0] = acc[2];
            sm[P1O + pb + 3 * 256 + g0] = acc[3];
        }
        __syncthreads();
        if (tid >= 256 && tid < 512) {  // combine1 zero-state
            float pi = sm[BS1O + jj], pg = sm[BS1O + 128 + jj], po = sm[BS1O + 192 + jj];
            {
                const float* pA = sm + P1O + 0 * 1024 + rr * 256;
                const float* pB = sm + P1O + 2 * 1024 + rr * 256;
                pi += pA[jj] + pB[jj];
                pg += pA[128 + jj] + pB[128 + jj];
                po += pA[192 + jj] + pB[192 + jj];
            }
            const float ig = sigm(pi), gg = tanh_(pg), og = sigm(po);
            sm[H1O + (tid & 255)] = og * tanh_(ig * gg);
        }
        __syncthreads();

        // ---- seg5: FC (tid<256): stride-1 b32 W_fc reads + uniform h1 b128 ----
        if (tid < 256) {
            float acc = bfc_j;
            const float4* hp = reinterpret_cast<const float4*>(sm + H1O + rr * 64);
#pragma unroll
            for (int k4 = 0; k4 < 16; ++k4) {
                const float4 hv = hp[k4];
                const float* wp = sm + WFCO + k4 * 256;
                acc = fmaf(hv.x, wp[jj],       acc);
                acc = fmaf(hv.y, wp[64 + jj],  acc);
                acc = fmaf(hv.z, wp[128 + jj], acc);
                acc = fmaf(hv.w, wp[192 + jj], acc);
            }
            out[(size_t)(row0 + rr) * PRED * DIM + p * DIM + jj] = acc;
            sm[DBO + tid] = acc;
        }
        __syncthreads();
    }
}

extern "C" void kernel_launch(void* const* d_in, const int* in_sizes, int n_in,
                              void* d_out, int out_size, void* d_ws, size_t ws_size,
                              hipStream_t stream) {
    const float* x    = (const float*)d_in[0];
    const float* Wih0 = (const float*)d_in[1];
    const float* Whh0 = (const float*)d_in[2];
    const float* bih0 = (const float*)d_in[3];
    const float* bhh0 = (const float*)d_in[4];
    const float* Wih1 = (const float*)d_in[5];
    const float* Whh1 = (const float*)d_in[6];
    const float* bih1 = (const float*)d_in[7];
    const float* bhh1 = (const float*)d_in[8];
    const float* Wfc  = (const float*)d_in[9];
    const float* bfc  = (const float*)d_in[10];
    float* out = (float*)d_out;

    hipLaunchKernelGGL(rnn_fused, dim3(NB / 4), dim3(THREADS), SMEM_BYTES, stream,
                       x, Wih0, Whh0, bih0, bhh0, Wih1, Whh1, bih1, bhh1, Wfc, bfc, out);
}